// Round 1
// 259.630 us; speedup vs baseline: 1.0487x; 1.0487x over previous
//
#include <hip/hip_runtime.h>

// GCN forward via two-level CSR build + gather aggregation (no atomics in the
// float path — R4/R9: atomic aggregation loses 5-10x to register gather).
//   binA2: per-block LDS radix partition -> 512 dst-range buckets (R14: 256
//     buckets left buildB at exactly 1 block/CU; 512 gives 2/CU).
//   buildB: per-bucket LDS histogram+scan -> counts/offs/dinv + CSR.
//   gemm1: xwd = (x@W1)*dinv, bf16 64B rows; R14: 4 nodes/thread register
//     blocking cuts LDS W-traffic 4x (was 1.6 GB ~ 23us LDS-bound).
//   aggF: layer-1 aggregate FUSED with gemm2 epilogue (R14): 4 lanes/node
//     gather (request-rate bound ~53us floor, R13), then per-lane 8x16
//     matvec from LDS W2 + 12-shuffle half-exchange butterfly -> h2wd bf16.
//     Eliminates the gemm2 dispatch and the 25 MB agg1 round trip.
//   aggS16f: 2 lanes/node + fused head (8 FMA + 1 shfl_xor) -> out.
// R7 lesson: no wave-serial (multi-step broadcast) epilogues in gather kernels
//   (the butterfly here is 12 shfl total, constant depth, no broadcast loop).
// R13 lesson: gather is request-rate bound — two L2-resident half-passes cost
//   MORE (35us x2); single pass is optimal.

#define TPB 256
#define NBUCK 512
#define BCAP 8192    // bucket capacity; mean ~6272, sd ~80 -> large margin
#define CHUNK 8192   // edges per binA2 block

__device__ __forceinline__ unsigned f2bf(float f) {  // RNE fp32->bf16
    unsigned u = __float_as_uint(f);
    return (u + 0x7FFFu + ((u >> 16) & 1u)) >> 16;
}
__device__ __forceinline__ float bflo(unsigned u) { return __uint_as_float(u << 16); }
__device__ __forceinline__ float bfhi(unsigned u) { return __uint_as_float(u & 0xFFFF0000u); }

// Phase A: block-local radix partition, then bulk append to global staging.
// 512 threads. buckb is ushort (bucket id needs 9 bits at NBUCK=512).
__global__ __launch_bounds__(512) void binA2_kernel(
        const int* __restrict__ src, const int* __restrict__ dst,
        int* __restrict__ bcur, unsigned* __restrict__ staging, int E, int NPB) {
    __shared__ unsigned packed[CHUNK];         // 32 KB
    __shared__ unsigned short buckb[CHUNK];    // 16 KB
    __shared__ int hist[NBUCK];
    __shared__ int scan_[NBUCK];
    __shared__ int lstart[NBUCK];
    __shared__ int lcur[NBUCK];
    __shared__ int gbase[NBUCK];
    int tid = threadIdx.x;
    int start = blockIdx.x * CHUNK;
    int sz = min(CHUNK, E - start);

    if (tid < NBUCK) hist[tid] = 0;
    __syncthreads();
    for (int i = tid; i < sz; i += 512) {
        unsigned d = (unsigned)dst[start + i];
        atomicAdd(&hist[d / (unsigned)NPB], 1);
    }
    __syncthreads();
    int v = (tid < NBUCK) ? hist[tid] : 0;
    if (tid < NBUCK) scan_[tid] = v;
    __syncthreads();
    for (int dd = 1; dd < NBUCK; dd <<= 1) {
        int t = 0;
        if (tid < NBUCK && tid >= dd) t = scan_[tid - dd];
        __syncthreads();
        if (tid < NBUCK) scan_[tid] += t;
        __syncthreads();
    }
    if (tid < NBUCK) {
        lstart[tid] = scan_[tid] - v;
        lcur[tid] = 0;
        gbase[tid] = atomicAdd(&bcur[tid], v);  // one reservation per (block,bucket)
    }
    __syncthreads();
    for (int i = tid; i < sz; i += 512) {
        unsigned d = (unsigned)dst[start + i];
        unsigned s = (unsigned)src[start + i];
        unsigned b = d / (unsigned)NPB;
        unsigned loc = d - b * (unsigned)NPB;
        int pos = atomicAdd(&lcur[b], 1);
        int si = lstart[b] + pos;
        packed[si] = (loc << 20) | s;          // loc<196 (8b), src<2^17
        buckb[si] = (unsigned short)b;
    }
    __syncthreads();
    for (int i = tid; i < sz; i += 512) {
        unsigned b = buckb[i];
        int dsti = gbase[b] + (i - lstart[b]);
        if (dsti < BCAP)
            staging[(size_t)b * BCAP + dsti] = packed[i];
    }
}

// Phase B: one block (512 thr) per bucket, 512 buckets -> 2 blocks/CU.
__global__ void buildB_kernel(const int* __restrict__ bcur,
                              const unsigned* __restrict__ staging,
                              int* __restrict__ offs, int* __restrict__ counts,
                              float* __restrict__ dinv, int* __restrict__ csr_src,
                              int N, int NPB) {
    __shared__ int sb[NBUCK];
    __shared__ int hist[512];
    __shared__ int scan_[512];
    __shared__ int cur[512];
    int b = blockIdx.x;
    int tid = threadIdx.x;
    // inclusive prefix of clamped bucket sizes over NBUCK entries
    if (tid < NBUCK) sb[tid] = min(bcur[tid], BCAP);
    __syncthreads();
    for (int d = 1; d < NBUCK; d <<= 1) {
        int t = 0;
        if (tid < NBUCK && tid >= d) t = sb[tid - d];
        __syncthreads();
        if (tid < NBUCK) sb[tid] += t;
        __syncthreads();
    }
    int sz = min(bcur[b], BCAP);
    int base = (b == 0) ? 0 : sb[b - 1];
    int n0 = b * NPB;
    int nn = min(NPB, N - n0);
    const unsigned* se = staging + (size_t)b * BCAP;

    hist[tid] = 0;
    __syncthreads();
    for (int i = tid; i < sz; i += 512)
        atomicAdd(&hist[se[i] >> 20], 1);
    __syncthreads();
    int h = hist[tid];
    scan_[tid] = h;
    __syncthreads();
    for (int d = 1; d < 512; d <<= 1) {
        int t = 0;
        if (tid >= d) t = scan_[tid - d];
        __syncthreads();
        scan_[tid] += t;
        __syncthreads();
    }
    int excl = scan_[tid] - h;
    cur[tid] = excl;
    if (tid < nn) {
        int node = n0 + tid;
        offs[node] = base + excl;
        counts[node] = h;
        dinv[node] = rsqrtf((float)(h + 1));  // +1 self-loop
    }
    __syncthreads();
    for (int i = tid; i < sz; i += 512) {
        unsigned p = se[i];
        int pos = atomicAdd(&cur[p >> 20], 1);
        csr_src[base + pos] = (int)(p & 0xFFFFFu);
    }
}

// xwd(bf16) = (x @ W1) * dinv[node].  4 threads/node x 8 cols x 4 nodes/thread;
// each LDS W-fragment feeds 4 nodes -> LDS traffic /4.  grid (N+255)/256.
__global__ __launch_bounds__(256) void gemm1_kernel(
        const float* __restrict__ x, const float* __restrict__ W1,
        const float* __restrict__ dinv, unsigned* __restrict__ xwd, int N) {
    __shared__ float ws_[128 * 32];
    for (int i = threadIdx.x; i < 128 * 32; i += 256) ws_[i] = W1[i];
    __syncthreads();
    int t = threadIdx.x;
    int jq = (t & 3) * 8;  // 8 output cols
    int n0 = blockIdx.x * 256 + (t >> 2) * 4;
    if (n0 >= N) return;
    int nc0 = min(n0 + 0, N - 1);
    int nc1 = min(n0 + 1, N - 1);
    int nc2 = min(n0 + 2, N - 1);
    int nc3 = min(n0 + 3, N - 1);
    const float4* xr0 = (const float4*)(x + (size_t)nc0 * 128);
    const float4* xr1 = (const float4*)(x + (size_t)nc1 * 128);
    const float4* xr2 = (const float4*)(x + (size_t)nc2 * 128);
    const float4* xr3 = (const float4*)(x + (size_t)nc3 * 128);
    float acc[4][8];
#pragma unroll
    for (int n = 0; n < 4; ++n)
#pragma unroll
        for (int j = 0; j < 8; ++j) acc[n][j] = 0.0f;
#pragma unroll 2
    for (int k4 = 0; k4 < 32; ++k4) {
        const float* wb = ws_ + (k4 * 4) * 32 + jq;
        float4 a0 = *(const float4*)(wb);
        float4 a1 = *(const float4*)(wb + 4);
        float4 b0 = *(const float4*)(wb + 32);
        float4 b1v = *(const float4*)(wb + 36);
        float4 c0 = *(const float4*)(wb + 64);
        float4 c1 = *(const float4*)(wb + 68);
        float4 d0 = *(const float4*)(wb + 96);
        float4 d1 = *(const float4*)(wb + 100);
        float4 xv0 = xr0[k4];
        float4 xv1 = xr1[k4];
        float4 xv2 = xr2[k4];
        float4 xv3 = xr3[k4];
#pragma unroll
        for (int n = 0; n < 4; ++n) {
            float4 xv = (n == 0) ? xv0 : (n == 1) ? xv1 : (n == 2) ? xv2 : xv3;
            acc[n][0] += xv.x * a0.x + xv.y * b0.x + xv.z * c0.x + xv.w * d0.x;
            acc[n][1] += xv.x * a0.y + xv.y * b0.y + xv.z * c0.y + xv.w * d0.y;
            acc[n][2] += xv.x * a0.z + xv.y * b0.z + xv.z * c0.z + xv.w * d0.z;
            acc[n][3] += xv.x * a0.w + xv.y * b0.w + xv.z * c0.w + xv.w * d0.w;
            acc[n][4] += xv.x * a1.x + xv.y * b1v.x + xv.z * c1.x + xv.w * d1.x;
            acc[n][5] += xv.x * a1.y + xv.y * b1v.y + xv.z * c1.y + xv.w * d1.y;
            acc[n][6] += xv.x * a1.z + xv.y * b1v.z + xv.z * c1.z + xv.w * d1.z;
            acc[n][7] += xv.x * a1.w + xv.y * b1v.w + xv.z * c1.w + xv.w * d1.w;
        }
    }
#pragma unroll
    for (int n = 0; n < 4; ++n) {
        int node = n0 + n;
        if (node >= N) break;
        float d = dinv[node];
        unsigned pk0 = f2bf(acc[n][0] * d) | (f2bf(acc[n][1] * d) << 16);
        unsigned pk1 = f2bf(acc[n][2] * d) | (f2bf(acc[n][3] * d) << 16);
        unsigned pk2 = f2bf(acc[n][4] * d) | (f2bf(acc[n][5] * d) << 16);
        unsigned pk3 = f2bf(acc[n][6] * d) | (f2bf(acc[n][7] * d) << 16);
        ((uint4*)(xwd + (size_t)node * 16))[t & 3] = make_uint4(pk0, pk1, pk2, pk3);
    }
}

// Layer-1 aggregate FUSED with gemm2: 4 lanes/node gather (unchanged geometry),
// then h2wd = (relu(agg*dv + b1) @ W2) * dv in-register.  Per lane: 8x16
// matvec from LDS W2, then half-exchange butterfly (8+4 shfl) so each lane
// ends with 4 full output cols -> 8B write.
__global__ __launch_bounds__(256) void aggF_kernel(
        const int* __restrict__ offs, const int* __restrict__ counts,
        const int* __restrict__ csr_src, const float* __restrict__ dinv,
        const unsigned* __restrict__ xwd, const float* __restrict__ b1,
        const float* __restrict__ W2, unsigned* __restrict__ h2wd, int N) {
    __shared__ float ws2[32 * 16];
    for (int i = threadIdx.x; i < 512; i += 256) ws2[i] = W2[i];
    __syncthreads();
    int t = threadIdx.x;
    int q = t & 3;                       // 16B slice
    int node = blockIdx.x * 64 + (t >> 2);
    if (node >= N) return;
    int off = offs[node];
    int deg = counts[node];
    float acc[8];
    {
        uint4 v = ((const uint4*)(xwd + (size_t)node * 16))[q];  // self term
        acc[0] = bflo(v.x); acc[1] = bfhi(v.x);
        acc[2] = bflo(v.y); acc[3] = bfhi(v.y);
        acc[4] = bflo(v.z); acc[5] = bfhi(v.z);
        acc[6] = bflo(v.w); acc[7] = bfhi(v.w);
    }
    int i = 0;
    for (; i + 1 < deg; i += 2) {
        int s0 = csr_src[off + i];
        int s1 = csr_src[off + i + 1];
        uint4 v0 = ((const uint4*)(xwd + (size_t)s0 * 16))[q];
        uint4 v1 = ((const uint4*)(xwd + (size_t)s1 * 16))[q];
        acc[0] += bflo(v0.x) + bflo(v1.x); acc[1] += bfhi(v0.x) + bfhi(v1.x);
        acc[2] += bflo(v0.y) + bflo(v1.y); acc[3] += bfhi(v0.y) + bfhi(v1.y);
        acc[4] += bflo(v0.z) + bflo(v1.z); acc[5] += bfhi(v0.z) + bfhi(v1.z);
        acc[6] += bflo(v0.w) + bflo(v1.w); acc[7] += bfhi(v0.w) + bfhi(v1.w);
    }
    if (i < deg) {
        int s = csr_src[off + i];
        uint4 v = ((const uint4*)(xwd + (size_t)s * 16))[q];
        acc[0] += bflo(v.x); acc[1] += bfhi(v.x);
        acc[2] += bflo(v.y); acc[3] += bfhi(v.y);
        acc[4] += bflo(v.z); acc[5] += bfhi(v.z);
        acc[6] += bflo(v.w); acc[7] += bfhi(v.w);
    }
    float dv = dinv[node];
    // fused gemm2: lane q owns k = q*8..q*8+7 of the 32-dim hidden vector
    float part[16];
#pragma unroll
    for (int j = 0; j < 16; ++j) part[j] = 0.0f;
    const float* bq = b1 + q * 8;
#pragma unroll
    for (int k = 0; k < 8; ++k) {
        float h = fmaxf(acc[k] * dv + bq[k], 0.0f);
        const float* wr = ws2 + (q * 8 + k) * 16;
        float4 w0 = *(const float4*)(wr);
        float4 w1 = *(const float4*)(wr + 4);
        float4 w2 = *(const float4*)(wr + 8);
        float4 w3 = *(const float4*)(wr + 12);
        part[0]  += h * w0.x; part[1]  += h * w0.y; part[2]  += h * w0.z; part[3]  += h * w0.w;
        part[4]  += h * w1.x; part[5]  += h * w1.y; part[6]  += h * w1.z; part[7]  += h * w1.w;
        part[8]  += h * w2.x; part[9]  += h * w2.y; part[10] += h * w2.z; part[11] += h * w2.w;
        part[12] += h * w3.x; part[13] += h * w3.y; part[14] += h * w3.z; part[15] += h * w3.w;
    }
    // half-exchange butterfly over the quad: 8 + 4 shfl total.
    // after step1 lane holds cols (q&1)*8 + j summed over k of {q, q^1}
    float p8[8];
#pragma unroll
    for (int j = 0; j < 8; ++j) {
        float send = (q & 1) ? part[j] : part[j + 8];
        float keep = (q & 1) ? part[j + 8] : part[j];
        p8[j] = keep + __shfl_xor(send, 1, 64);
    }
    // after step2 lane holds full sums for cols (q&1)*8 + ((q&2)?4:0) + j
    float p4[4];
#pragma unroll
    for (int j = 0; j < 4; ++j) {
        float send = (q & 2) ? p8[j] : p8[j + 4];
        float keep = (q & 2) ? p8[j + 4] : p8[j];
        p4[j] = keep + __shfl_xor(send, 2, 64);
    }
    unsigned pk0 = f2bf(p4[0] * dv) | (f2bf(p4[1] * dv) << 16);
    unsigned pk1 = f2bf(p4[2] * dv) | (f2bf(p4[3] * dv) << 16);
    int slot = ((q & 1) << 1) | ((q >> 1) & 1);   // col base /4: q0->0 q1->2 q2->1 q3->3
    ((uint2*)(h2wd + (size_t)node * 8))[slot] = make_uint2(pk0, pk1);
}

// Layer-2 aggregate + fused head, lane-slice: 2 lanes own node's 32B row;
// serial edges (x2 unroll); epilogue = 8 FMA dot + ONE shfl_xor -> out.
__global__ __launch_bounds__(256) void aggS16f_kernel(
        const int* __restrict__ offs, const int* __restrict__ counts,
        const int* __restrict__ csr_src, const float* __restrict__ dinv,
        const unsigned* __restrict__ h2wd,
        const float* __restrict__ b2, const float* __restrict__ Wf,
        const float* __restrict__ bf, float* __restrict__ out, int N) {
    __shared__ float bs_[16];
    __shared__ float wf_[16];
    __shared__ float bfv;
    int t = threadIdx.x;
    if (t < 16) { bs_[t] = b2[t]; wf_[t] = Wf[t]; }
    if (t == 0) bfv = bf[0];
    __syncthreads();
    int q = t & 1;                        // 16B slice (8 feats)
    int node = blockIdx.x * 128 + (t >> 1);
    if (node >= N) return;
    int off = offs[node];
    int deg = counts[node];
    float acc[8];
    {
        uint4 v = ((const uint4*)(h2wd + (size_t)node * 8))[q];  // self term
        acc[0] = bflo(v.x); acc[1] = bfhi(v.x);
        acc[2] = bflo(v.y); acc[3] = bfhi(v.y);
        acc[4] = bflo(v.z); acc[5] = bfhi(v.z);
        acc[6] = bflo(v.w); acc[7] = bfhi(v.w);
    }
    int i = 0;
    for (; i + 1 < deg; i += 2) {
        int s0 = csr_src[off + i];
        int s1 = csr_src[off + i + 1];
        uint4 v0 = ((const uint4*)(h2wd + (size_t)s0 * 8))[q];
        uint4 v1 = ((const uint4*)(h2wd + (size_t)s1 * 8))[q];
        acc[0] += bflo(v0.x) + bflo(v1.x); acc[1] += bfhi(v0.x) + bfhi(v1.x);
        acc[2] += bflo(v0.y) + bflo(v1.y); acc[3] += bfhi(v0.y) + bfhi(v1.y);
        acc[4] += bflo(v0.z) + bflo(v1.z); acc[5] += bfhi(v0.z) + bfhi(v1.z);
        acc[6] += bflo(v0.w) + bflo(v1.w); acc[7] += bfhi(v0.w) + bfhi(v1.w);
    }
    if (i < deg) {
        int s = csr_src[off + i];
        uint4 v = ((const uint4*)(h2wd + (size_t)s * 8))[q];
        acc[0] += bflo(v.x); acc[1] += bfhi(v.x);
        acc[2] += bflo(v.y); acc[3] += bfhi(v.y);
        acc[4] += bflo(v.z); acc[5] += bfhi(v.z);
        acc[6] += bflo(v.w); acc[7] += bfhi(v.w);
    }
    // fused head: out[node] = relu(acc*dv + b2) . Wf + bf  (pair-split dot)
    float dv = dinv[node];
    const float* bq = bs_ + q * 8;
    const float* wq = wf_ + q * 8;
    float part = 0.f;
#pragma unroll
    for (int k = 0; k < 8; ++k)
        part += fmaxf(acc[k] * dv + bq[k], 0.f) * wq[k];
    part += __shfl_xor(part, 1, 64);  // combine the pair's halves
    if (q == 0) out[node] = part + bfv;
}

extern "C" void kernel_launch(void* const* d_in, const int* in_sizes, int n_in,
                              void* d_out, int out_size, void* d_ws, size_t ws_size,
                              hipStream_t stream) {
    const float* x  = (const float*)d_in[0];
    const int*   ei = (const int*)d_in[1];
    const float* W1 = (const float*)d_in[2];
    const float* b1 = (const float*)d_in[3];
    const float* W2 = (const float*)d_in[4];
    const float* b2 = (const float*)d_in[5];
    const float* Wf = (const float*)d_in[6];
    const float* bf = (const float*)d_in[7];

    int N = in_sizes[0] / 128;
    int E = in_sizes[1] / 2;
    const int* src = ei;       // edge_index[0]
    const int* dst = ei + E;   // edge_index[1]
    int NPB = (N + NBUCK - 1) / NBUCK;  // 196 for N=100k

    // Workspace layout
    size_t Np = ((size_t)N + 3) & ~(size_t)3;
    size_t Ep = ((size_t)E + 3) & ~(size_t)3;
    int* wsI      = (int*)d_ws;
    int* counts   = wsI;                 // N
    int* offs     = counts + Np;         // N
    int* bcur     = offs + Np;           // NBUCK
    int* csr_src  = bcur + NBUCK;        // E
    float* dinv   = (float*)(csr_src + Ep);      // N
    unsigned* xwd = (unsigned*)(dinv + Np);      // 16*N u32 (bf16 rows, 64B)
    unsigned* staging = xwd + 16 * Np;           // NBUCK*BCAP u32 = 16.8 MB
    // h2wd (8*N u32 = 3.2 MB) aliases staging: staging written by binA2,
    // read last by buildB; h2wd first written by aggF (later). No overlap.
    unsigned* h2wd = staging;
    float* out    = (float*)d_out;

    int nbG1 = (N + 255) / 256;  // 4 thr/node x 4 nodes/thread
    int nbC  = (E + CHUNK - 1) / CHUNK;
    int nbA32 = (N + 63) / 64;   // 64 nodes/block (4 lanes/node)
    int nbA16 = (N + 127) / 128; // 128 nodes/block (2 lanes/node)

    hipMemsetAsync(bcur, 0, NBUCK * sizeof(int), stream);
    binA2_kernel<<<nbC, 512, 0, stream>>>(src, dst, bcur, staging, E, NPB);
    buildB_kernel<<<NBUCK, 512, 0, stream>>>(bcur, staging, offs, counts,
                                             dinv, csr_src, N, NPB);
    gemm1_kernel<<<nbG1, 256, 0, stream>>>(x, W1, dinv, xwd, N);
    aggF_kernel<<<nbA32, 256, 0, stream>>>(offs, counts, csr_src, dinv, xwd,
                                           b1, W2, h2wd, N);
    aggS16f_kernel<<<nbA16, 256, 0, stream>>>(offs, counts, csr_src, dinv, h2wd,
                                              b2, Wf, bf, out, N);
}